// Round 3
// baseline (430.350 us; speedup 1.0000x reference)
//
#include <hip/hip_runtime.h>

#define BB  65536
#define INW 128
#define HH  256
#define MM  32
#define KK  (INW + HH)   // 384
#define NKC 12           // 32-wide K chunks in the main GEMM

typedef __attribute__((ext_vector_type(8))) short bf16x8;
typedef __attribute__((ext_vector_type(4))) float f32x4;

__device__ __forceinline__ unsigned short f32_to_bf16(float f) {
    union { float f; unsigned u; } v; v.f = f;
    return (unsigned short)((v.u + 0x7fffu + ((v.u >> 16) & 1u)) >> 16);
}

__device__ __forceinline__ bf16x8 cvt8(f32x4 a, f32x4 b) {
    bf16x8 r;
    r[0] = (short)f32_to_bf16(a[0]); r[1] = (short)f32_to_bf16(a[1]);
    r[2] = (short)f32_to_bf16(a[2]); r[3] = (short)f32_to_bf16(a[3]);
    r[4] = (short)f32_to_bf16(b[0]); r[5] = (short)f32_to_bf16(b[1]);
    r[6] = (short)f32_to_bf16(b[2]); r[7] = (short)f32_to_bf16(b[3]);
    return r;
}

__device__ __forceinline__ float rcp_f(float x) { return __builtin_amdgcn_rcpf(x); }
__device__ __forceinline__ float sigmoid_f(float x) { return rcp_f(1.0f + __expf(-x)); }
__device__ __forceinline__ float tanh_f(float x) { return 1.0f - 2.0f * rcp_f(__expf(2.0f * x) + 1.0f); }

// ---- weight fp32 -> bf16, packed fragment-major (same as R2) ----
// Wi packed: half h (n0=h*128) | kc in [0,12) | t in [0,8) | lane*8+j
//   element = Wi[(h*128 + t*16 + (lane&15)) * KK + kc*32 + (lane>>4)*8 + j]
// Wm packed: half h | t in [0,8) | lane*8+j
__global__ void pack_weights(const float* __restrict__ Wi, const float* __restrict__ Wm,
                             unsigned short* __restrict__ Wi_p, unsigned short* __restrict__ Wm_p) {
    int id = blockIdx.x * 256 + threadIdx.x;
    if (id < 2 * NKC * 8 * 512) {
        int blk = id >> 9;
        int e   = id & 511;
        int lane = e >> 3, j = e & 7;
        int lrow = lane & 15, quad = lane >> 4;
        int h  = blk / (NKC * 8);
        int b  = blk % (NKC * 8);
        int kc = b >> 3;
        int t  = b & 7;
        int n  = h * 128 + t * 16 + lrow;
        int k  = kc * 32 + quad * 8 + j;
        Wi_p[id] = f32_to_bf16(Wi[(size_t)n * KK + k]);
    }
    if (id < 2 * 8 * 512) {
        int blk = id >> 9;
        int e   = id & 511;
        int lane = e >> 3, j = e & 7;
        int lrow = lane & 15, quad = lane >> 4;
        int h = blk >> 3;
        int t = blk & 7;
        int n = h * 128 + t * 16 + lrow;
        Wm_p[id] = f32_to_bf16(Wm[(size_t)n * MM + quad * 8 + j]);
    }
}

// ---- fused RLSTM: 32 batch rows x 128 cols per wave, two m-tiles share
// every weight fragment. D = W_frag x X_frag; C/D: col(lane&15)=batch,
// row(quad*4+r)=n -> float4 epilogue per lane.
__global__ __launch_bounds__(256) void rlstm_main(
    const float* __restrict__ input, const float* __restrict__ media,
    const float* __restrict__ h_t,   const float* __restrict__ c_t,
    const unsigned short* __restrict__ Wi_p, const float* __restrict__ bi,
    const unsigned short* __restrict__ Wm_p, const float* __restrict__ bm,
    float* __restrict__ out)
{
    const int tid  = threadIdx.x;
    const int wave = tid >> 6;
    const int lane = tid & 63;
    const int lrow = lane & 15;
    const int quad = lane >> 4;

    const int half = wave & 1;
    const int m0   = blockIdx.x * 64 + (wave >> 1) * 32;  // 32 batch rows/wave
    const int n0   = half * 128;

    const unsigned short* wip = Wi_p + (size_t)half * (NKC * 8 * 512);
    const unsigned short* wmp = Wm_p + (size_t)half * (8 * 512);

    const int arowA = m0 + lrow;        // m-tile A rows
    const int arowB = m0 + 16 + lrow;   // m-tile B rows

    f32x4 accA[8], accB[8];
#pragma unroll
    for (int t = 0; t < 8; ++t) {
        accA[t] = (f32x4){0.f, 0.f, 0.f, 0.f};
        accB[t] = (f32x4){0.f, 0.f, 0.f, 0.f};
    }

    // ---- main GEMM: k in [0,128) from input, [128,384) from h_t ----
#pragma unroll
    for (int kc = 0; kc < NKC; ++kc) {
        const float* srcA = (kc < 4)
            ? (input + (size_t)arowA * INW + kc * 32 + quad * 8)
            : (h_t   + (size_t)arowA * HH  + (kc - 4) * 32 + quad * 8);
        const float* srcB = (kc < 4)
            ? (input + (size_t)arowB * INW + kc * 32 + quad * 8)
            : (h_t   + (size_t)arowB * HH  + (kc - 4) * 32 + quad * 8);
        f32x4 a0 = ((const f32x4*)srcA)[0];
        f32x4 a1 = ((const f32x4*)srcA)[1];
        f32x4 b0 = ((const f32x4*)srcB)[0];
        f32x4 b1 = ((const f32x4*)srcB)[1];
        bf16x8 xfA = cvt8(a0, a1);
        bf16x8 xfB = cvt8(b0, b1);
        const unsigned short* wb = wip + (size_t)kc * (8 * 512) + lane * 8;
#pragma unroll
        for (int t = 0; t < 8; ++t) {
            bf16x8 wf = *(const bf16x8*)(wb + t * 512);
            accA[t] = __builtin_amdgcn_mfma_f32_16x16x32_bf16(wf, xfA, accA[t], 0, 0, 0);
            accB[t] = __builtin_amdgcn_mfma_f32_16x16x32_bf16(wf, xfB, accB[t], 0, 0, 0);
        }
    }

    // ---- epilogue: media MFMA lazily per tile; nt loads/stores for stream data
    bf16x8 mfA = cvt8(*(const f32x4*)(media + (size_t)arowA * MM + quad * 8),
                      *(const f32x4*)(media + (size_t)arowA * MM + quad * 8 + 4));
    bf16x8 mfB = cvt8(*(const f32x4*)(media + (size_t)arowB * MM + quad * 8),
                      *(const f32x4*)(media + (size_t)arowB * MM + quad * 8 + 4));
    const size_t outH = (size_t)BB * HH;
    const size_t rowbaseA = (size_t)arowA * HH;
    const size_t rowbaseB = (size_t)arowB * HH;

#pragma unroll
    for (int t = 0; t < 8; ++t) {
        bf16x8 wmf = *(const bf16x8*)(wmp + t * 512 + lane * 8);
        f32x4 amA = __builtin_amdgcn_mfma_f32_16x16x32_bf16(
            wmf, mfA, (f32x4){0.f, 0.f, 0.f, 0.f}, 0, 0, 0);
        f32x4 amB = __builtin_amdgcn_mfma_f32_16x16x32_bf16(
            wmf, mfB, (f32x4){0.f, 0.f, 0.f, 0.f}, 0, 0, 0);

        const int nb = n0 + t * 16 + quad * 4;
        f32x4 bi4 = *(const f32x4*)(bi + nb);
        f32x4 bm4 = *(const f32x4*)(bm + nb);

#pragma unroll
        for (int mt = 0; mt < 2; ++mt) {
            const size_t idx = (mt ? rowbaseB : rowbaseA) + nb;
            const f32x4* accp = mt ? accB : accA;
            const f32x4  am   = mt ? amB : amA;
            f32x4 ct4 = __builtin_nontemporal_load((const f32x4*)(c_t + idx));
            f32x4 h4, c4;
#pragma unroll
            for (int r = 0; r < 4; ++r) {
                float g    = accp[t][r] + bi4[r];
                float mp   = am[r] + bm4[r];
                float gate = sigmoid_f(g);
                float tg   = tanh_f(g);
                float c    = ct4[r] * gate + tg * gate;
                float cr   = tanh_f(c);
                float mg   = sigmoid_f(mp);
                float cf   = c - cr + cr * mg;
                float h    = tanh_f(cf) * gate;
                h4[r] = h; c4[r] = c;
            }
            __builtin_nontemporal_store(h4, (f32x4*)(out + idx));
            __builtin_nontemporal_store(h4, (f32x4*)(out + idx + outH));
            __builtin_nontemporal_store(c4, (f32x4*)(out + idx + 2 * outH));
        }
    }
}

extern "C" void kernel_launch(void* const* d_in, const int* in_sizes, int n_in,
                              void* d_out, int out_size, void* d_ws, size_t ws_size,
                              hipStream_t stream) {
    const float* input = (const float*)d_in[0];
    const float* media = (const float*)d_in[1];
    const float* h_t   = (const float*)d_in[2];
    const float* c_t   = (const float*)d_in[3];
    const float* Wi    = (const float*)d_in[4];
    const float* bi    = (const float*)d_in[5];
    const float* Wm    = (const float*)d_in[6];
    const float* bm    = (const float*)d_in[7];
    float* out = (float*)d_out;

    unsigned short* Wi_p = (unsigned short*)d_ws;
    unsigned short* Wm_p = Wi_p + 2 * NKC * 8 * 512;

    hipLaunchKernelGGL(pack_weights, dim3((2 * NKC * 8 * 512 + 255) / 256), dim3(256), 0, stream,
                       Wi, Wm, Wi_p, Wm_p);
    hipLaunchKernelGGL(rlstm_main, dim3(BB / 64), dim3(256), 0, stream,
                       input, media, h_t, c_t, Wi_p, bi, Wm_p, bm, out);
}